// Round 13
// baseline (108.732 us; speedup 1.0000x reference)
//
#include <hip/hip_runtime.h>
#include <math.h>

typedef unsigned int uint;
typedef unsigned short ushort;
typedef short s16x8 __attribute__((ext_vector_type(8)));
typedef float f32x4 __attribute__((ext_vector_type(4)));
typedef uint u32x4 __attribute__((ext_vector_type(4)));

#define L     880
#define LP    896
#define NC    64
#define WSZ   (NC * LP)
#define DS    48
#define OUTD  96
#define KCV   3072
#define NZ    6

// ws layout (float offsets). 11 bf16 E planes (401408 floats each) at 0.
// KDT (bf16, 896x3072) OVERLAYS planes 0-3 (EN1/ET1/EN2/ET2, dead after L2; first KDT write in L5).
#define OFF_E    0
#define OFF_KDT  0
#define OFF_WF   4415488                    // 32 slabs f32 (W0..W31)
#define OFF_WB   (OFF_WF + 32 * WSZ)        // 32 slabs bf16
#define OFF_U    (OFF_WB + 32 * WSZ / 2)    // 256x3072 bf16
#define OFF_PART (OFF_U + 256 * KCV / 2)    // NZ x 256 x 896 f32
#define OFF_PHI  (OFF_PART + NZ * 256 * LP) // 192 x 896 f32
// total 9109504 floats = 36.4 MiB

#define LROW 72
#define LBUF (64 * LROW)
#define LGRP (2 * LBUF)

__device__ inline ushort f2b(float f) {
  uint u = __builtin_bit_cast(uint, f);
  u += 0x7fffu + ((u >> 16) & 1u);
  return (ushort)(u >> 16);
}
__device__ inline float b2f(ushort b) {
  uint u = ((uint)b) << 16;
  return __builtin_bit_cast(float, u);
}

// ---- 64x64 split-K MFMA core (verified r10/r12) ----
__device__ __forceinline__ void mma_core(const ushort* __restrict__ aptr,
                                         const ushort* __restrict__ bptr,
                                         int KH, int tid, ushort* ldsA, ushort* ldsB,
                                         f32x4 acc[2][2]) {
  const int grp = tid >> 8;
  const int t2  = tid & 255;
  const int gL  = grp * LGRP;
  const int r = t2 >> 2, kq = (t2 & 3) * 16;
  const int wv = t2 >> 6, lane = tid & 63;
  const int wm = (wv >> 1) * 32, wn = (wv & 1) * 32;
  const int lr = lane & 15, lg = lane >> 4;
  acc[0][0] = f32x4{0.f, 0.f, 0.f, 0.f};
  acc[0][1] = f32x4{0.f, 0.f, 0.f, 0.f};
  acc[1][0] = f32x4{0.f, 0.f, 0.f, 0.f};
  acc[1][1] = f32x4{0.f, 0.f, 0.f, 0.f};
  u32x4 ra0 = *(const u32x4*)aptr;
  u32x4 ra1 = *(const u32x4*)(aptr + 8);
  u32x4 rb0 = *(const u32x4*)bptr;
  u32x4 rb1 = *(const u32x4*)(bptr + 8);
  __syncthreads();
  *(u32x4*)&ldsA[gL + r * LROW + kq]     = ra0;
  *(u32x4*)&ldsA[gL + r * LROW + kq + 8] = ra1;
  *(u32x4*)&ldsB[gL + r * LROW + kq]     = rb0;
  *(u32x4*)&ldsB[gL + r * LROW + kq + 8] = rb1;
  if (KH > 1) {
    ra0 = *(const u32x4*)(aptr + 64);  ra1 = *(const u32x4*)(aptr + 72);
    rb0 = *(const u32x4*)(bptr + 64);  rb1 = *(const u32x4*)(bptr + 72);
  }
  __syncthreads();
  for (int it = 0; it < KH; ++it) {
    const int cur = gL + (it & 1) * LBUF;
    const int nxt = gL + ((it & 1) ^ 1) * LBUF;
    s16x8 fa0[2], fa1[2], fb0[2], fb1[2];
#pragma unroll
    for (int k2 = 0; k2 < 2; ++k2) {
      fa0[k2] = *(const s16x8*)&ldsA[cur + (wm + lr) * LROW + k2 * 32 + lg * 8];
      fa1[k2] = *(const s16x8*)&ldsA[cur + (wm + 16 + lr) * LROW + k2 * 32 + lg * 8];
      fb0[k2] = *(const s16x8*)&ldsB[cur + (wn + lr) * LROW + k2 * 32 + lg * 8];
      fb1[k2] = *(const s16x8*)&ldsB[cur + (wn + 16 + lr) * LROW + k2 * 32 + lg * 8];
    }
    if (it + 1 < KH) {
      *(u32x4*)&ldsA[nxt + r * LROW + kq]     = ra0;
      *(u32x4*)&ldsA[nxt + r * LROW + kq + 8] = ra1;
      *(u32x4*)&ldsB[nxt + r * LROW + kq]     = rb0;
      *(u32x4*)&ldsB[nxt + r * LROW + kq + 8] = rb1;
      if (it + 2 < KH) {
        ra0 = *(const u32x4*)(aptr + (it + 2) * 64);
        ra1 = *(const u32x4*)(aptr + (it + 2) * 64 + 8);
        rb0 = *(const u32x4*)(bptr + (it + 2) * 64);
        rb1 = *(const u32x4*)(bptr + (it + 2) * 64 + 8);
      }
    }
#pragma unroll
    for (int k2 = 0; k2 < 2; ++k2) {
      acc[0][0] = __builtin_amdgcn_mfma_f32_16x16x32_bf16(fa0[k2], fb0[k2], acc[0][0], 0, 0, 0);
      acc[0][1] = __builtin_amdgcn_mfma_f32_16x16x32_bf16(fa0[k2], fb1[k2], acc[0][1], 0, 0, 0);
      acc[1][0] = __builtin_amdgcn_mfma_f32_16x16x32_bf16(fa1[k2], fb0[k2], acc[1][0], 0, 0, 0);
      acc[1][1] = __builtin_amdgcn_mfma_f32_16x16x32_bf16(fa1[k2], fb1[k2], acc[1][1], 0, 0, 0);
    }
    __syncthreads();
  }
  float* red = (float*)ldsA;
  if (grp == 1) {
#pragma unroll
    for (int m = 0; m < 2; ++m)
#pragma unroll
      for (int n = 0; n < 2; ++n)
#pragma unroll
        for (int rr = 0; rr < 4; ++rr)
          red[((m * 2 + n) * 4 + rr) * 256 + t2] = acc[m][n][rr];
  }
  __syncthreads();
  if (grp == 0) {
#pragma unroll
    for (int m = 0; m < 2; ++m)
#pragma unroll
      for (int n = 0; n < 2; ++n)
#pragma unroll
        for (int rr = 0; rr < 4; ++rr)
          acc[m][n][rr] += red[((m * 2 + n) * 4 + rr) * 256 + t2];
  }
}

// ---- A staged as bf16(f32 slab-diff), coalesced (verified r12) ----
__device__ __forceinline__ void mma_core_f32A(const float* __restrict__ ap1,
                                              const float* __restrict__ ap0,
                                              const ushort* __restrict__ bptr,
                                              int KH, int tid, ushort* ldsA, ushort* ldsB,
                                              f32x4 acc[2][2]) {
  const int grp = tid >> 8;
  const int t2  = tid & 255;
  const int gL  = grp * LGRP;
  const int r = t2 >> 2, kq = (t2 & 3) * 16;
  const int wv = t2 >> 6, lane = tid & 63;
  const int wm = (wv >> 1) * 32, wn = (wv & 1) * 32;
  const int lr = lane & 15, lg = lane >> 4;
  acc[0][0] = f32x4{0.f, 0.f, 0.f, 0.f};
  acc[0][1] = f32x4{0.f, 0.f, 0.f, 0.f};
  acc[1][0] = f32x4{0.f, 0.f, 0.f, 0.f};
  acc[1][1] = f32x4{0.f, 0.f, 0.f, 0.f};
  float4 ca[4], pa[4];
  auto issueA = [&](int it) {
#pragma unroll
    for (int i = 0; i < 4; ++i) {
      ca[i] = *(const float4*)(ap1 + it * 64 + i * 4);
      pa[i] = *(const float4*)(ap0 + it * 64 + i * 4);
    }
  };
  auto packA = [&](int buf) {
    union { ushort s[16]; u32x4 v[2]; } pk;
#pragma unroll
    for (int i = 0; i < 4; ++i) {
      pk.s[i * 4 + 0] = f2b(ca[i].x - pa[i].x);
      pk.s[i * 4 + 1] = f2b(ca[i].y - pa[i].y);
      pk.s[i * 4 + 2] = f2b(ca[i].z - pa[i].z);
      pk.s[i * 4 + 3] = f2b(ca[i].w - pa[i].w);
    }
    *(u32x4*)&ldsA[buf + r * LROW + kq]     = pk.v[0];
    *(u32x4*)&ldsA[buf + r * LROW + kq + 8] = pk.v[1];
  };
  u32x4 rb0 = *(const u32x4*)bptr;
  u32x4 rb1 = *(const u32x4*)(bptr + 8);
  issueA(0);
  __syncthreads();
  packA(gL);
  *(u32x4*)&ldsB[gL + r * LROW + kq]     = rb0;
  *(u32x4*)&ldsB[gL + r * LROW + kq + 8] = rb1;
  if (KH > 1) {
    rb0 = *(const u32x4*)(bptr + 64);
    rb1 = *(const u32x4*)(bptr + 72);
    issueA(1);
  }
  __syncthreads();
  for (int it = 0; it < KH; ++it) {
    const int cur = gL + (it & 1) * LBUF;
    const int nxt = gL + ((it & 1) ^ 1) * LBUF;
    s16x8 fa0[2], fa1[2], fb0[2], fb1[2];
#pragma unroll
    for (int k2 = 0; k2 < 2; ++k2) {
      fa0[k2] = *(const s16x8*)&ldsA[cur + (wm + lr) * LROW + k2 * 32 + lg * 8];
      fa1[k2] = *(const s16x8*)&ldsA[cur + (wm + 16 + lr) * LROW + k2 * 32 + lg * 8];
      fb0[k2] = *(const s16x8*)&ldsB[cur + (wn + lr) * LROW + k2 * 32 + lg * 8];
      fb1[k2] = *(const s16x8*)&ldsB[cur + (wn + 16 + lr) * LROW + k2 * 32 + lg * 8];
    }
    if (it + 1 < KH) {
      packA(nxt);
      *(u32x4*)&ldsB[nxt + r * LROW + kq]     = rb0;
      *(u32x4*)&ldsB[nxt + r * LROW + kq + 8] = rb1;
      if (it + 2 < KH) {
        rb0 = *(const u32x4*)(bptr + (it + 2) * 64);
        rb1 = *(const u32x4*)(bptr + (it + 2) * 64 + 8);
        issueA(it + 2);
      }
    }
#pragma unroll
    for (int k2 = 0; k2 < 2; ++k2) {
      acc[0][0] = __builtin_amdgcn_mfma_f32_16x16x32_bf16(fa0[k2], fb0[k2], acc[0][0], 0, 0, 0);
      acc[0][1] = __builtin_amdgcn_mfma_f32_16x16x32_bf16(fa0[k2], fb1[k2], acc[0][1], 0, 0, 0);
      acc[1][0] = __builtin_amdgcn_mfma_f32_16x16x32_bf16(fa1[k2], fb0[k2], acc[1][0], 0, 0, 0);
      acc[1][1] = __builtin_amdgcn_mfma_f32_16x16x32_bf16(fa1[k2], fb1[k2], acc[1][1], 0, 0, 0);
    }
    __syncthreads();
  }
  float* red = (float*)ldsA;
  if (grp == 1) {
#pragma unroll
    for (int m = 0; m < 2; ++m)
#pragma unroll
      for (int n = 0; n < 2; ++n)
#pragma unroll
        for (int rr = 0; rr < 4; ++rr)
          red[((m * 2 + n) * 4 + rr) * 256 + t2] = acc[m][n][rr];
  }
  __syncthreads();
  if (grp == 0) {
#pragma unroll
    for (int m = 0; m < 2; ++m)
#pragma unroll
      for (int n = 0; n < 2; ++n)
#pragma unroll
        for (int rr = 0; rr < 4; ++rr)
          acc[m][n][rr] += red[((m * 2 + n) * 4 + rr) * 256 + t2];
  }
}

// ---- KD-chain task: KDT col-block j = coef*KDs_s + KDs_s.E (verified r12 k_tail path) ----
__device__ __forceinline__ void kdchain_task(const float* __restrict__ WF,
                                             const ushort* __restrict__ E, float coef,
                                             int s, int j, int n0, int tid, int kg,
                                             ushort* ldsA, ushort* ldsB,
                                             ushort* __restrict__ KDT) {
  const int t2 = tid & 255;
  const int r = t2 >> 2;
  const int wv = t2 >> 6, lane = tid & 63;
  const int wm = (wv >> 1) * 32, wn = (wv & 1) * 32;
  const int lr = lane & 15, lg = lane >> 4;
  const float* ap1 = WF + (size_t)s * WSZ + (size_t)r * LP + kg;
  f32x4 acc[2][2];
  mma_core_f32A(ap1, ap1 - WSZ, E + (size_t)(n0 + r) * LP + kg, 7, tid, ldsA, ldsB, acc);
  ushort* T = ldsB;
  if (tid < 256) {
#pragma unroll
    for (int fm = 0; fm < 2; ++fm)
#pragma unroll
      for (int fn = 0; fn < 2; ++fn)
#pragma unroll
        for (int rr = 0; rr < 4; ++rr) {
          int mi = wm + fm * 16 + lg * 4 + rr;
          if (mi < 48) {
            int ni = n0 + wn + fn * 16 + lr;
            float kds = WF[(size_t)s * WSZ + (size_t)mi * LP + ni]
                      - WF[(size_t)(s - 1) * WSZ + (size_t)mi * LP + ni];
            float v = acc[fm][fn][rr] + coef * kds;
            T[(wn + fn * 16 + lr) * LROW + mi] = f2b(v);
          }
        }
  }
  __syncthreads();
  if (tid < 384) {
    int row = tid / 6, seg = tid - row * 6;
    *(u32x4*)(KDT + (size_t)(n0 + row) * KCV + j * 48 + seg * 8)
        = *(const u32x4*)&T[row * LROW + seg * 8];
  }
}

// ---- kd memory task (j=0 -> W0; j=63 -> zeros) ----
__device__ __forceinline__ void kd_body(const float* __restrict__ WF, ushort* __restrict__ KDT,
                                        int j, int l0, int tid, float (*D)[65]) {
  __syncthreads();
  if (j < 63) {
    const float* Wj = WF + (size_t)j * WSZ;
    for (int e = tid; e < 48 * 64; e += 512) {
      int d = e >> 6, ll = e & 63;
      float v = Wj[d * LP + l0 + ll];
      if (j > 0) v -= Wj[-(int)WSZ + d * LP + l0 + ll];
      D[d][ll] = v;
    }
  } else {
    for (int e = tid; e < 48 * 64; e += 512) { int d = e >> 6, ll = e & 63; D[d][ll] = 0.f; }
  }
  __syncthreads();
  for (int e = tid; e < 48 * 64; e += 512) {
    int ll = e / 48, d = e - ll * 48;
    KDT[(size_t)(l0 + ll) * KCV + j * 48 + d] = f2b(D[d][ll]);
  }
}

// ================= fused prep: E1(N+T) | W0 | U  (256 threads) =================
__global__ __launch_bounds__(256) void k_prep(const float* __restrict__ A,
                                              const float* __restrict__ B,
                                              const float* __restrict__ th0,
                                              const float* __restrict__ xs,
                                              ushort* __restrict__ EN,
                                              ushort* __restrict__ ET,
                                              float* __restrict__ WF,
                                              ushort* __restrict__ WB,
                                              ushort* __restrict__ U) {
  const int blk = blockIdx.x;
  const int tid = threadIdx.x;
  if (blk < 196) {
    __shared__ float T[64][65];
    const int bi = (blk / 14) * 64, bj = (blk % 14) * 64;
    const int r = tid >> 2, c0 = (tid & 3) * 16;
    const int gi = bi + r;
#pragma unroll
    for (int q = 0; q < 4; ++q) {
      int c = c0 + q * 4, gj = bj + c;
      float4 v = {0.f, 0.f, 0.f, 0.f};
      if (gi < L && gj + 3 < L) {
        v = *(const float4*)(A + (size_t)gi * L + gj);
      } else if (gi < L) {
        if (gj + 0 < L) v.x = A[(size_t)gi * L + gj];
        if (gj + 1 < L) v.y = A[(size_t)gi * L + gj + 1];
        if (gj + 2 < L) v.z = A[(size_t)gi * L + gj + 2];
        if (gj + 3 < L) v.w = A[(size_t)gi * L + gj + 3];
      }
      if (gi == gj)     v.x -= 0.99f;
      if (gi == gj + 1) v.y -= 0.99f;
      if (gi == gj + 2) v.z -= 0.99f;
      if (gi == gj + 3) v.w -= 0.99f;
      T[r][c] = v.x; T[r][c + 1] = v.y; T[r][c + 2] = v.z; T[r][c + 3] = v.w;
    }
    __syncthreads();
    {
      union { ushort s[16]; u32x4 v[2]; } pk;
#pragma unroll
      for (int i = 0; i < 16; ++i) pk.s[i] = f2b(T[r][c0 + i]);
      *(u32x4*)(EN + (size_t)(bi + r) * LP + bj + c0)     = pk.v[0];
      *(u32x4*)(EN + (size_t)(bi + r) * LP + bj + c0 + 8) = pk.v[1];
    }
    {
      union { ushort s[16]; u32x4 v[2]; } pk;
#pragma unroll
      for (int i = 0; i < 16; ++i) pk.s[i] = f2b(T[c0 + i][r]);
      *(u32x4*)(ET + (size_t)(bj + r) * LP + bi + c0)     = pk.v[0];
      *(u32x4*)(ET + (size_t)(bj + r) * LP + bi + c0 + 8) = pk.v[1];
    }
  } else if (blk < 210) {
    int base = (blk - 196) * 4096;
    for (int e = tid; e < 4096; e += 256) {
      int idx = base + e;
      int c = idx / LP, l = idx % LP;
      float v = 0.f;
      if (l < L) {
        if (c < DS) v = B[l * DS + c];
        else if (c == DS) v = th0[l];
        else if (c < 53) {
          int b = c - 49;
          float s = 0.f;
          for (int d = 0; d < DS; ++d) s += B[l * DS + d] * xs[(b * 64) * DS + d];
          v = -s;
        }
      }
      WF[idx] = v;
      WB[idx] = f2b(v);
    }
  } else {
    int idx = ((blk - 210) * 256 + tid) * 4;
    int rr = idx / KCV, k = idx - rr * KCV;
    ushort4 v = {0, 0, 0, 0};
    if (rr < 252 && k < 3024) {
      int b = rr / 63, tau = rr - b * 63;
      int j = k / DS, d = k - j * DS;
      int s = tau - j; if (s < 0) s += 63;
      float4 x4 = *(const float4*)(xs + (size_t)(b * 64 + s + 1) * DS + d);
      v.x = f2b(x4.x); v.y = f2b(x4.y); v.z = f2b(x4.z); v.w = f2b(x4.w);
    }
    *(ushort4*)(U + idx) = v;
  }
}

// ========== ladder L1-L4 (512 thr): [sq | chain] ==========
__global__ __launch_bounds__(512, 4) void k_ladder(
    const ushort* __restrict__ sqA, const ushort* __restrict__ sqBT, float cs2,
    ushort* __restrict__ sqOutN, ushort* __restrict__ sqOutT, int ySq,
    int nCh, const ushort* __restrict__ chWB, const ushort* __restrict__ chE, float csc,
    const float* __restrict__ chWFsrc, float* __restrict__ chWFdst,
    ushort* __restrict__ chWBdst) {
  __shared__ __align__(16) ushort ldsA[2 * LGRP];
  __shared__ __align__(16) ushort ldsB[2 * LGRP];
  const int tid = threadIdx.x;
  const int y = blockIdx.y;
  const int n0 = blockIdx.x * 64;
  const int t2 = tid & 255, grp = tid >> 8;
  const int r = t2 >> 2, kq = (t2 & 3) * 16;
  const int kg = grp * 448 + kq;
  const int wv = t2 >> 6, lane = tid & 63;
  const int wm = (wv >> 1) * 32, wn = (wv & 1) * 32;
  const int lr = lane & 15, lg = lane >> 4;

  if (y < ySq) {
    const int m0 = y * 64;
    f32x4 acc[2][2];
    mma_core(sqA + (size_t)(m0 + r) * LP + kg, sqBT + (size_t)(n0 + r) * LP + kg,
             7, tid, ldsA, ldsB, acc);
    ushort* T = ldsB;
    if (tid < 256) {
#pragma unroll
      for (int fm = 0; fm < 2; ++fm)
#pragma unroll
        for (int fn = 0; fn < 2; ++fn)
#pragma unroll
          for (int rr = 0; rr < 4; ++rr) {
            int mi = wm + fm * 16 + lg * 4 + rr;
            int ni = wn + fn * 16 + lr;
            float v = acc[fm][fn][rr] + cs2 * b2f(sqA[(size_t)(m0 + mi) * LP + n0 + ni]);
            ushort bv = f2b(v);
            sqOutN[(size_t)(m0 + mi) * LP + n0 + ni] = bv;
            T[ni * LROW + mi] = bv;
          }
    }
    __syncthreads();
    if (sqOutT && tid < 256) {
      const int nr = tid >> 2, ct0 = (tid & 3) * 16;
      u32x4 o0 = *(const u32x4*)&T[nr * LROW + ct0];
      u32x4 o1 = *(const u32x4*)&T[nr * LROW + ct0 + 8];
      *(u32x4*)(sqOutT + (size_t)(n0 + nr) * LP + m0 + ct0)     = o0;
      *(u32x4*)(sqOutT + (size_t)(n0 + nr) * LP + m0 + ct0 + 8) = o1;
    }
  } else {
    const int t = y - ySq;
    f32x4 acc[2][2];
    mma_core(chWB + (size_t)t * WSZ + (size_t)r * LP + kg,
             chE + (size_t)(n0 + r) * LP + kg, 7, tid, ldsA, ldsB, acc);
    if (tid < 256) {
      const float*  srcF = chWFsrc + (size_t)t * WSZ;
      float*        dstF = chWFdst + (size_t)t * WSZ;
      ushort*       dstB = chWBdst + (size_t)t * WSZ;
#pragma unroll
      for (int fm = 0; fm < 2; ++fm)
#pragma unroll
        for (int fn = 0; fn < 2; ++fn)
#pragma unroll
          for (int rr = 0; rr < 4; ++rr) {
            int mi = wm + fm * 16 + lg * 4 + rr;
            int ni = n0 + wn + fn * 16 + lr;
            float v = acc[fm][fn][rr] + csc * srcF[(size_t)mi * LP + ni];
            dstF[(size_t)mi * LP + ni] = v;
            dstB[(size_t)mi * LP + ni] = f2b(v);
          }
    }
  }
}

// ========== L5 (512 thr): sq E32 | chain W16..31 | kd-mem j0..15 | KD-chain j16..31 ==========
__global__ __launch_bounds__(512, 4) void k_mid(
    const ushort* __restrict__ EN8, const ushort* __restrict__ EN16,
    const ushort* __restrict__ ET16, ushort* __restrict__ EN32,
    float c8v, float c16v,
    ushort* __restrict__ WB, float* __restrict__ WF,
    ushort* __restrict__ KDT) {
  __shared__ __align__(16) ushort ldsA[2 * LGRP];
  __shared__ __align__(16) ushort ldsB[2 * LGRP];
  const int tid = threadIdx.x;
  const int y = blockIdx.y;
  const int n0 = blockIdx.x * 64;
  const int t2 = tid & 255, grp = tid >> 8;
  const int r = t2 >> 2, kq = (t2 & 3) * 16;
  const int kg = grp * 448 + kq;
  const int wv = t2 >> 6, lane = tid & 63;
  const int wm = (wv >> 1) * 32, wn = (wv & 1) * 32;
  const int lr = lane & 15, lg = lane >> 4;

  if (y < 14) {                                // sq: E32 = E16^2 + 2c16*E16 (no transpose out)
    const int m0 = y * 64;
    f32x4 acc[2][2];
    mma_core(EN16 + (size_t)(m0 + r) * LP + kg, ET16 + (size_t)(n0 + r) * LP + kg,
             7, tid, ldsA, ldsB, acc);
    if (tid < 256) {
#pragma unroll
      for (int fm = 0; fm < 2; ++fm)
#pragma unroll
        for (int fn = 0; fn < 2; ++fn)
#pragma unroll
          for (int rr = 0; rr < 4; ++rr) {
            int mi = wm + fm * 16 + lg * 4 + rr;
            int ni = wn + fn * 16 + lr;
            float v = acc[fm][fn][rr] + 2.f * c16v * b2f(EN16[(size_t)(m0 + mi) * LP + n0 + ni]);
            EN32[(size_t)(m0 + mi) * LP + n0 + ni] = f2b(v);
          }
    }
  } else if (y < 30) {                         // chain: W_{t+16} = c16*W_t + W_t.E16
    const int t = y - 14;
    f32x4 acc[2][2];
    mma_core(WB + (size_t)t * WSZ + (size_t)r * LP + kg,
             EN16 + (size_t)(n0 + r) * LP + kg, 7, tid, ldsA, ldsB, acc);
    if (tid < 256) {
      const float*  srcF = WF + (size_t)t * WSZ;
      float*        dstF = WF + (size_t)(t + 16) * WSZ;
      ushort*       dstB = WB + (size_t)(t + 16) * WSZ;
#pragma unroll
      for (int fm = 0; fm < 2; ++fm)
#pragma unroll
        for (int fn = 0; fn < 2; ++fn)
#pragma unroll
          for (int rr = 0; rr < 4; ++rr) {
            int mi = wm + fm * 16 + lg * 4 + rr;
            int ni = n0 + wn + fn * 16 + lr;
            float v = acc[fm][fn][rr] + c16v * srcF[(size_t)mi * LP + ni];
            dstF[(size_t)mi * LP + ni] = v;
            dstB[(size_t)mi * LP + ni] = f2b(v);
          }
    }
  } else if (y < 46) {                         // kd-mem j=0..15
    kd_body(WF, KDT, y - 30, n0, tid, (float(*)[65])ldsA);
  } else if (y == 46) {                        // KD_16 = c8*KDs_8 + KDs_8.E8
    kdchain_task(WF, EN8, c8v, 8, 16, n0, tid, kg, ldsA, ldsB, KDT);
  } else {                                     // KD_j (j=17..31) = c16*KDs_{j-16} + KDs.E16
    int j = 17 + (y - 47);
    kdchain_task(WF, EN16, c16v, j - 16, j, n0, tid, kg, ldsA, ldsB, KDT);
  }
}

// ========== L6 (512 thr): PHI | KD-chain j32..62 | kd63 | conv z=0..2 ==========
__global__ __launch_bounds__(512, 4) void k_tail(
    const ushort* __restrict__ WB, const float* __restrict__ WF,
    const ushort* __restrict__ EN16, const ushort* __restrict__ EN32,
    float c16v, float c32v, float* __restrict__ PHI, ushort* __restrict__ KDT,
    const ushort* __restrict__ U, float* __restrict__ part) {
  __shared__ __align__(16) ushort ldsA[2 * LGRP];
  __shared__ __align__(16) ushort ldsB[2 * LGRP];
  const int tid = threadIdx.x;
  const int y = blockIdx.y;
  const int n0 = blockIdx.x * 64;
  const int t2 = tid & 255, grp = tid >> 8;
  const int r = t2 >> 2, kq = (t2 & 3) * 16;
  const int kg = grp * 448 + kq;
  const int wv = t2 >> 6, lane = tid & 63;
  const int wm = (wv >> 1) * 32, wn = (wv & 1) * 32;
  const int lr = lane & 15, lg = lane >> 4;

  if (y < 3) {                                 // PHI rows i=t*5+q: theta/sig cols of W32..62
    const int m0 = y * 64;
    int i = m0 + r; if (i > 154) i = 154;
    int t = i / 5, q = i - t * 5;
    f32x4 acc[2][2];
    mma_core(WB + (size_t)t * WSZ + (size_t)(48 + q) * LP + kg,
             EN32 + (size_t)(n0 + r) * LP + kg, 7, tid, ldsA, ldsB, acc);
    if (tid < 256) {
#pragma unroll
      for (int fm = 0; fm < 2; ++fm)
#pragma unroll
        for (int fn = 0; fn < 2; ++fn)
#pragma unroll
          for (int rr = 0; rr < 4; ++rr) {
            int mi = wm + fm * 16 + lg * 4 + rr;
            int ni = n0 + wn + fn * 16 + lr;
            int io = m0 + mi;
            int ic = io > 154 ? 154 : io;
            int tt = ic / 5, qq = ic - tt * 5;
            float v = acc[fm][fn][rr] + c32v * WF[(size_t)tt * WSZ + (size_t)(48 + qq) * LP + ni];
            PHI[(size_t)io * LP + ni] = v;
          }
    }
  } else if (y < 34) {                         // KD-chain j=32..62
    const int kt = y - 3;
    if (kt == 0) kdchain_task(WF, EN16, c16v, 16, 32, n0, tid, kg, ldsA, ldsB, KDT);
    else         kdchain_task(WF, EN32, c32v, kt, kt + 32, n0, tid, kg, ldsA, ldsB, KDT);
  } else if (y == 34) {                        // kd63 zero pad
    kd_body(WF, KDT, 63, n0, tid, (float(*)[65])ldsA);
  } else {                                     // conv z=0..2 (KDT j<=31 ready after L5)
    const int c = y - 35;
    const int z = c >> 2, m0 = (c & 3) * 64;
    const int kgc = z * 512 + grp * 256 + kq;
    f32x4 acc[2][2];
    mma_core(U + (size_t)(m0 + r) * KCV + kgc, KDT + (size_t)(n0 + r) * KCV + kgc,
             4, tid, ldsA, ldsB, acc);
    if (tid < 256) {
      float* pp = part + (size_t)z * (256 * LP);
#pragma unroll
      for (int fm = 0; fm < 2; ++fm)
#pragma unroll
        for (int fn = 0; fn < 2; ++fn)
#pragma unroll
          for (int rr = 0; rr < 4; ++rr) {
            int m = m0 + wm + fm * 16 + lg * 4 + rr;
            int n = n0 + wn + fn * 16 + lr;
            pp[(size_t)m * LP + n] = acc[fm][fn][rr];
          }
    }
  }
}

// ========== conv z=3..5 (512 thr) ==========
__global__ __launch_bounds__(512, 4) void k_conv(const ushort* __restrict__ U,
                                                 const ushort* __restrict__ KDT,
                                                 float* __restrict__ part) {
  __shared__ __align__(16) ushort ldsA[2 * LGRP];
  __shared__ __align__(16) ushort ldsB[2 * LGRP];
  const int tid = threadIdx.x;
  const int n0 = blockIdx.x * 64, m0 = blockIdx.y * 64;
  const int z = 3 + blockIdx.z;
  const int t2 = tid & 255, grp = tid >> 8;
  const int r = t2 >> 2, kq = (t2 & 3) * 16;
  const int kgc = z * 512 + grp * 256 + kq;
  const int wv = t2 >> 6, lane = tid & 63;
  const int wm = (wv >> 1) * 32, wn = (wv & 1) * 32;
  const int lr = lane & 15, lg = lane >> 4;
  f32x4 acc[2][2];
  mma_core(U + (size_t)(m0 + r) * KCV + kgc, KDT + (size_t)(n0 + r) * KCV + kgc,
           4, tid, ldsA, ldsB, acc);
  if (tid < 256) {
    float* pp = part + (size_t)z * (256 * LP);
#pragma unroll
    for (int fm = 0; fm < 2; ++fm)
#pragma unroll
      for (int fn = 0; fn < 2; ++fn)
#pragma unroll
        for (int rr = 0; rr < 4; ++rr) {
          int m = m0 + wm + fm * 16 + lg * 4 + rr;
          int n = n0 + wn + fn * 16 + lr;
          pp[(size_t)m * LP + n] = acc[fm][fn][rr];
        }
  }
}

// ================= final: assemble theta row in LDS, decode =================
__global__ __launch_bounds__(256) void k_final(const float* __restrict__ part,
                                               const float* __restrict__ PHI,
                                               const float* __restrict__ WF,
                                               const float* __restrict__ th0,
                                               const float* __restrict__ ts,
                                               float* __restrict__ out) {
  __shared__ float th[LP];
  const int bt = blockIdx.x, b = bt >> 6, t = bt & 63;
  for (int l = threadIdx.x; l < LP; l += 256) {
    float v = 0.f;
    if (l < L) {
      if (t == 0) v = th0[l];
      else {
        int rr = b * 63 + (t - 1);
#pragma unroll
        for (int z = 0; z < NZ; ++z) v += part[(size_t)z * (256 * LP) + rr * LP + l];
        int tau = t - 1;
        v += (tau < 32) ? WF[(size_t)tau * WSZ + DS * LP + l]
                        : PHI[(size_t)((tau - 32) * 5) * LP + l];
        int tw = (tau + 62) % 63;
        v += (tw < 32) ? WF[(size_t)tw * WSZ + (49 + b) * LP + l]
                       : PHI[(size_t)((tw - 32) * 5 + 1 + b) * LP + l];
      }
    }
    th[l] = v;
  }
  __syncthreads();
  int o = threadIdx.x;
  if (o < OUTD) {
    float tv = ts[bt];
    float acc = th[784 + o];
#pragma unroll
    for (int i = 0; i < 8; ++i) {
      float h = fmaxf(th[i] * tv + th[8 + i], 0.f);
      acc += th[16 + o * 8 + i] * h;
    }
    float rs;
    if (o < DS) rs = tanhf(acc);
    else        rs = fmaxf(acc, 0.f) + log1pf(expf(-fabsf(acc)));
    out[bt * OUTD + o] = rs;
  }
}

extern "C" void kernel_launch(void* const* d_in, const int* in_sizes, int n_in,
                              void* d_out, int out_size, void* d_ws, size_t ws_size,
                              hipStream_t stream) {
  const float* xs  = (const float*)d_in[0];
  const float* ts  = (const float*)d_in[1];
  const float* th0 = (const float*)d_in[2];
  const float* A   = (const float*)d_in[3];
  const float* B   = (const float*)d_in[4];
  float* out = (float*)d_out;
  float* ws  = (float*)d_ws;

  ushort* EP   = (ushort*)(ws + OFF_E);
  const size_t PL = (size_t)LP * LP;
  ushort* EN1  = EP + 0 * PL;
  ushort* ET1  = EP + 1 * PL;
  ushort* EN2  = EP + 2 * PL;
  ushort* ET2  = EP + 3 * PL;
  ushort* EN4  = EP + 4 * PL;
  ushort* ET4  = EP + 5 * PL;
  ushort* EN8  = EP + 6 * PL;
  ushort* ET8  = EP + 7 * PL;
  ushort* EN16 = EP + 8 * PL;
  ushort* ET16 = EP + 9 * PL;
  ushort* EN32 = EP + 10 * PL;
  float*  WF   = ws + OFF_WF;
  ushort* WB   = (ushort*)(ws + OFF_WB);
  ushort* KDT  = (ushort*)(ws + OFF_KDT);     // overlays E planes 0-3 (dead after L2)
  ushort* U    = (ushort*)(ws + OFF_U);
  float*  part = ws + OFF_PART;
  float*  PHI  = ws + OFF_PHI;

  const float c1 = 0.99f;
  const float c2 = c1 * c1, c4 = c2 * c2, c8 = c4 * c4, c16 = c8 * c8, c32 = c16 * c16;

  k_prep<<<978, 256, 0, stream>>>(A, B, th0, xs, EN1, ET1, WF, WB, U);

  k_ladder<<<dim3(14, 15), 512, 0, stream>>>(EN1, ET1, 2.f * c1, EN2, ET2, 14,
                                             1, WB, EN1, c1, WF, WF + 1 * WSZ, WB + (size_t)1 * WSZ);
  k_ladder<<<dim3(14, 16), 512, 0, stream>>>(EN2, ET2, 2.f * c2, EN4, ET4, 14,
                                             2, WB, EN2, c2, WF, WF + 2 * WSZ, WB + (size_t)2 * WSZ);
  k_ladder<<<dim3(14, 18), 512, 0, stream>>>(EN4, ET4, 2.f * c4, EN8, ET8, 14,
                                             4, WB, EN4, c4, WF, WF + 4 * WSZ, WB + (size_t)4 * WSZ);
  k_ladder<<<dim3(14, 22), 512, 0, stream>>>(EN8, ET8, 2.f * c8, EN16, ET16, 14,
                                             8, WB, EN8, c8, WF, WF + 8 * WSZ, WB + (size_t)8 * WSZ);
  // L5: sq E32 | chain W16..31 | kd j=0..15 | KD-chain j=16..31
  k_mid<<<dim3(14, 62), 512, 0, stream>>>(EN8, EN16, ET16, EN32, c8, c16, WB, WF, KDT);
  // L6: PHI | KD-chain j=32..62 | kd63 | conv z=0..2
  k_tail<<<dim3(14, 47), 512, 0, stream>>>(WB, WF, EN16, EN32, c16, c32, PHI, KDT, U, part);
  // conv z=3..5
  k_conv<<<dim3(14, 4, 3), 512, 0, stream>>>(U, KDT, part);
  k_final<<<256, 256, 0, stream>>>(part, PHI, WF, th0, ts, out);
}

// Round 14
// 93.188 us; speedup vs baseline: 1.1668x; 1.1668x over previous
//
#include <hip/hip_runtime.h>
#include <math.h>

typedef unsigned int uint;
typedef unsigned short ushort;
typedef short s16x8 __attribute__((ext_vector_type(8)));
typedef float f32x4 __attribute__((ext_vector_type(4)));
typedef uint u32x4 __attribute__((ext_vector_type(4)));

#define L     880
#define LP    896
#define NC    64
#define WSZ   (NC * LP)
#define DS    48
#define OUTD  96
#define KCV   3072
#define NZ    6

// ws layout (float offsets). 11 bf16 E planes (401408 floats each) at 0.
// KDT (bf16, LP*KCV shorts) OVERLAYS planes 0..3.5 (EN1/ET1/EN2/ET2), dead after L5.
#define OFF_E    0
#define OFF_KDT  0
#define OFF_WF   4415488                    // 63 slabs f32
#define OFF_WB   (OFF_WF + 63 * WSZ)        // 63 slabs bf16
#define OFF_U    (OFF_WB + 63 * WSZ / 2)    // 256x3072 bf16
#define OFF_PART (OFF_U + 256 * KCV / 2)    // NZ x 256 x 896 f32
// total 11603968 floats = 46.4 MiB

// LDS geometry for the split-K GEMM: per group 2 dbuf x 64 rows x 72 pitch (ushort)
#define LROW   72
#define LBUF   (64 * LROW)        // 4608 ushorts per buffer
#define LGRP   (2 * LBUF)         // per-group area

__device__ inline ushort f2b(float f) {
  uint u = __builtin_bit_cast(uint, f);
  u += 0x7fffu + ((u >> 16) & 1u);
  return (ushort)(u >> 16);
}
__device__ inline float b2f(ushort b) {
  uint u = ((uint)b) << 16;
  return __builtin_bit_cast(float, u);
}

// ---- 64x64xK GEMM, in-block split-K over 2 wave-groups (512 threads) ----
// C[m][n] = sum_k Ag[m][k]*Bg[n][k]. Group g covers k-half g. After the loop,
// group 1 dumps acc to LDS (conflict-free layout), group 0 merges; epilogue is
// done by tid<256 using the same (wv,lane) mapping as the 256-thread version.
__device__ __forceinline__ void gemm64sk(const ushort* __restrict__ Ag,
                                         const ushort* __restrict__ Bg,
                                         int Kdim, int kIters, int kOff, int m0, int n0,
                                         int tid, ushort* ldsA, ushort* ldsB,
                                         f32x4 acc[2][2]) {
  const int grp = tid >> 8;
  const int t2  = tid & 255;
  const int KH  = kIters >> 1;                 // iters per group (kIters even)
  const int gL  = grp * LGRP;
  const int kOffG = kOff + grp * KH * 64;
  const int r = t2 >> 2, kq = (t2 & 3) * 16;
  const ushort* aptr = Ag + (size_t)(m0 + r) * Kdim + kOffG + kq;
  const ushort* bptr = Bg + (size_t)(n0 + r) * Kdim + kOffG + kq;
  const int wv = t2 >> 6, lane = tid & 63;
  const int wm = (wv >> 1) * 32, wn = (wv & 1) * 32;
  const int lr = lane & 15, lg = lane >> 4;
  acc[0][0] = f32x4{0.f, 0.f, 0.f, 0.f};
  acc[0][1] = f32x4{0.f, 0.f, 0.f, 0.f};
  acc[1][0] = f32x4{0.f, 0.f, 0.f, 0.f};
  acc[1][1] = f32x4{0.f, 0.f, 0.f, 0.f};
  u32x4 ra0 = *(const u32x4*)aptr;
  u32x4 ra1 = *(const u32x4*)(aptr + 8);
  u32x4 rb0 = *(const u32x4*)bptr;
  u32x4 rb1 = *(const u32x4*)(bptr + 8);
  __syncthreads();                             // LDS reuse guard
  *(u32x4*)&ldsA[gL + r * LROW + kq]     = ra0;
  *(u32x4*)&ldsA[gL + r * LROW + kq + 8] = ra1;
  *(u32x4*)&ldsB[gL + r * LROW + kq]     = rb0;
  *(u32x4*)&ldsB[gL + r * LROW + kq + 8] = rb1;
  if (KH > 1) {
    ra0 = *(const u32x4*)(aptr + 64);
    ra1 = *(const u32x4*)(aptr + 72);
    rb0 = *(const u32x4*)(bptr + 64);
    rb1 = *(const u32x4*)(bptr + 72);
  }
  __syncthreads();                             // stage(0) visible
  for (int it = 0; it < KH; ++it) {
    const int cur = gL + (it & 1) * LBUF;
    const int nxt = gL + ((it & 1) ^ 1) * LBUF;
    s16x8 fa0[2], fa1[2], fb0[2], fb1[2];
#pragma unroll
    for (int k2 = 0; k2 < 2; ++k2) {
      fa0[k2] = *(const s16x8*)&ldsA[cur + (wm + lr) * LROW + k2 * 32 + lg * 8];
      fa1[k2] = *(const s16x8*)&ldsA[cur + (wm + 16 + lr) * LROW + k2 * 32 + lg * 8];
      fb0[k2] = *(const s16x8*)&ldsB[cur + (wn + lr) * LROW + k2 * 32 + lg * 8];
      fb1[k2] = *(const s16x8*)&ldsB[cur + (wn + 16 + lr) * LROW + k2 * 32 + lg * 8];
    }
    if (it + 1 < KH) {                         // stage next tile (other buffer) under MFMA wait
      *(u32x4*)&ldsA[nxt + r * LROW + kq]     = ra0;
      *(u32x4*)&ldsA[nxt + r * LROW + kq + 8] = ra1;
      *(u32x4*)&ldsB[nxt + r * LROW + kq]     = rb0;
      *(u32x4*)&ldsB[nxt + r * LROW + kq + 8] = rb1;
      if (it + 2 < KH) {
        ra0 = *(const u32x4*)(aptr + (it + 2) * 64);
        ra1 = *(const u32x4*)(aptr + (it + 2) * 64 + 8);
        rb0 = *(const u32x4*)(bptr + (it + 2) * 64);
        rb1 = *(const u32x4*)(bptr + (it + 2) * 64 + 8);
      }
    }
#pragma unroll
    for (int k2 = 0; k2 < 2; ++k2) {
      acc[0][0] = __builtin_amdgcn_mfma_f32_16x16x32_bf16(fa0[k2], fb0[k2], acc[0][0], 0, 0, 0);
      acc[0][1] = __builtin_amdgcn_mfma_f32_16x16x32_bf16(fa0[k2], fb1[k2], acc[0][1], 0, 0, 0);
      acc[1][0] = __builtin_amdgcn_mfma_f32_16x16x32_bf16(fa1[k2], fb0[k2], acc[1][0], 0, 0, 0);
      acc[1][1] = __builtin_amdgcn_mfma_f32_16x16x32_bf16(fa1[k2], fb1[k2], acc[1][1], 0, 0, 0);
    }
    __syncthreads();
  }
  // ---- cross-group reduce: red[e*256 + t2] (conflict-free: consecutive lanes -> banks)
  float* red = (float*)ldsA;
  if (grp == 1) {
#pragma unroll
    for (int m = 0; m < 2; ++m)
#pragma unroll
      for (int n = 0; n < 2; ++n)
#pragma unroll
        for (int rr = 0; rr < 4; ++rr)
          red[((m * 2 + n) * 4 + rr) * 256 + t2] = acc[m][n][rr];
  }
  __syncthreads();
  if (grp == 0) {
#pragma unroll
    for (int m = 0; m < 2; ++m)
#pragma unroll
      for (int n = 0; n < 2; ++n)
#pragma unroll
        for (int rr = 0; rr < 4; ++rr)
          acc[m][n][rr] += red[((m * 2 + n) * 4 + rr) * 256 + t2];
  }
}

// ---- kd task (512 threads): KDT[l0..+63][j*48+d] = W_j[d][l]-W_{j-1}[d][l] (j=63 pad) ----
__device__ __forceinline__ void kd_body(const float* __restrict__ WF, ushort* __restrict__ KDT,
                                        int j, int l0, int tid, float (*D)[65]) {
  __syncthreads();
  if (j < 63) {
    const float* Wj = WF + (size_t)j * WSZ;
    for (int e = tid; e < 48 * 64; e += 512) {
      int d = e >> 6, ll = e & 63;
      float v = Wj[d * LP + l0 + ll];
      if (j > 0) v -= Wj[-(int)WSZ + d * LP + l0 + ll];
      D[d][ll] = v;
    }
  } else {
    for (int e = tid; e < 48 * 64; e += 512) { int d = e >> 6, ll = e & 63; D[d][ll] = 0.f; }
  }
  __syncthreads();
  for (int e = tid; e < 48 * 64; e += 512) {
    int ll = e / 48, d = e - ll * 48;
    KDT[(size_t)(l0 + ll) * KCV + j * 48 + d] = f2b(D[d][ll]);
  }
}

// ================= fused prep: E1(N+T) | W0 | U  (256 threads) =================
__global__ __launch_bounds__(256) void k_prep(const float* __restrict__ A,
                                              const float* __restrict__ B,
                                              const float* __restrict__ th0,
                                              const float* __restrict__ xs,
                                              ushort* __restrict__ EN,
                                              ushort* __restrict__ ET,
                                              float* __restrict__ WF,
                                              ushort* __restrict__ WB,
                                              ushort* __restrict__ U) {
  const int blk = blockIdx.x;
  const int tid = threadIdx.x;
  if (blk < 196) {
    __shared__ float T[64][65];
    const int bi = (blk / 14) * 64, bj = (blk % 14) * 64;
    const int r = tid >> 2, c0 = (tid & 3) * 16;
    const int gi = bi + r;
#pragma unroll
    for (int q = 0; q < 4; ++q) {
      int c = c0 + q * 4, gj = bj + c;
      float4 v = {0.f, 0.f, 0.f, 0.f};
      if (gi < L && gj + 3 < L) {
        v = *(const float4*)(A + (size_t)gi * L + gj);
      } else if (gi < L) {
        if (gj + 0 < L) v.x = A[(size_t)gi * L + gj];
        if (gj + 1 < L) v.y = A[(size_t)gi * L + gj + 1];
        if (gj + 2 < L) v.z = A[(size_t)gi * L + gj + 2];
        if (gj + 3 < L) v.w = A[(size_t)gi * L + gj + 3];
      }
      if (gi == gj)     v.x -= 0.99f;
      if (gi == gj + 1) v.y -= 0.99f;
      if (gi == gj + 2) v.z -= 0.99f;
      if (gi == gj + 3) v.w -= 0.99f;
      T[r][c] = v.x; T[r][c + 1] = v.y; T[r][c + 2] = v.z; T[r][c + 3] = v.w;
    }
    __syncthreads();
    {
      union { ushort s[16]; u32x4 v[2]; } pk;
#pragma unroll
      for (int i = 0; i < 16; ++i) pk.s[i] = f2b(T[r][c0 + i]);
      *(u32x4*)(EN + (size_t)(bi + r) * LP + bj + c0)     = pk.v[0];
      *(u32x4*)(EN + (size_t)(bi + r) * LP + bj + c0 + 8) = pk.v[1];
    }
    {
      union { ushort s[16]; u32x4 v[2]; } pk;
#pragma unroll
      for (int i = 0; i < 16; ++i) pk.s[i] = f2b(T[c0 + i][r]);
      *(u32x4*)(ET + (size_t)(bj + r) * LP + bi + c0)     = pk.v[0];
      *(u32x4*)(ET + (size_t)(bj + r) * LP + bi + c0 + 8) = pk.v[1];
    }
  } else if (blk < 210) {
    int base = (blk - 196) * 4096;
    for (int e = tid; e < 4096; e += 256) {
      int idx = base + e;
      int c = idx / LP, l = idx % LP;
      float v = 0.f;
      if (l < L) {
        if (c < DS) v = B[l * DS + c];
        else if (c == DS) v = th0[l];
        else if (c < 53) {
          int b = c - 49;
          float s = 0.f;
          for (int d = 0; d < DS; ++d) s += B[l * DS + d] * xs[(b * 64) * DS + d];
          v = -s;
        }
      }
      WF[idx] = v;
      WB[idx] = f2b(v);
    }
  } else {
    int idx = ((blk - 210) * 256 + tid) * 4;   // 768 blocks cover 256*KCV
    int rr = idx / KCV, k = idx - rr * KCV;
    ushort4 v = {0, 0, 0, 0};
    if (rr < 252 && k < 3024) {
      int b = rr / 63, tau = rr - b * 63;
      int j = k / DS, d = k - j * DS;
      int s = tau - j; if (s < 0) s += 63;
      float4 x4 = *(const float4*)(xs + (size_t)(b * 64 + s + 1) * DS + d);
      v.x = f2b(x4.x); v.y = f2b(x4.y); v.z = f2b(x4.z); v.w = f2b(x4.w);
    }
    *(ushort4*)(U + idx) = v;
  }
}

// ================= ladder (512 thr): [sq | chain | kd] by blockIdx.y =================
__global__ __launch_bounds__(512, 4) void k_ladder(
    const ushort* __restrict__ sqA, const ushort* __restrict__ sqBT, float cs2,
    ushort* __restrict__ sqOutN, ushort* __restrict__ sqOutT, int ySq,
    int nCh, const ushort* __restrict__ chWB, const ushort* __restrict__ chE, float csc,
    const float* __restrict__ chWFsrc, float* __restrict__ chWFdst,
    ushort* __restrict__ chWBdst,
    int kdJ0, const float* __restrict__ kdWF, ushort* __restrict__ kdKDT) {
  __shared__ __align__(16) ushort ldsA[2 * LGRP];
  __shared__ __align__(16) ushort ldsB[2 * LGRP];
  const int tid = threadIdx.x;
  const int y = blockIdx.y;
  const int n0 = blockIdx.x * 64;
  const int wv = (tid & 255) >> 6, lane = tid & 63;
  const int wm = (wv >> 1) * 32, wn = (wv & 1) * 32;
  const int lr = lane & 15, lg = lane >> 4;

  if (y < ySq) {                         // ---- square: E_2S = E_S^2 + cs2*E_S ----
    const int m0 = y * 64;
    f32x4 acc[2][2];
    gemm64sk(sqA, sqBT, LP, LP / 64, 0, m0, n0, tid, ldsA, ldsB, acc);
    ushort* T = ldsB;                    // [64][LROW] bounce, group-0 region
    if (tid < 256) {
#pragma unroll
      for (int fm = 0; fm < 2; ++fm)
#pragma unroll
        for (int fn = 0; fn < 2; ++fn)
#pragma unroll
          for (int rr = 0; rr < 4; ++rr) {
            int mi = wm + fm * 16 + lg * 4 + rr;
            int ni = wn + fn * 16 + lr;
            float v = acc[fm][fn][rr] + cs2 * b2f(sqA[(size_t)(m0 + mi) * LP + n0 + ni]);
            ushort bv = f2b(v);
            sqOutN[(size_t)(m0 + mi) * LP + n0 + ni] = bv;
            T[ni * LROW + mi] = bv;
          }
    }
    __syncthreads();
    if (sqOutT && tid < 256) {
      const int nr = tid >> 2, ct0 = (tid & 3) * 16;
      u32x4 o0 = *(const u32x4*)&T[nr * LROW + ct0];
      u32x4 o1 = *(const u32x4*)&T[nr * LROW + ct0 + 8];
      *(u32x4*)(sqOutT + (size_t)(n0 + nr) * LP + m0 + ct0)     = o0;
      *(u32x4*)(sqOutT + (size_t)(n0 + nr) * LP + m0 + ct0 + 8) = o1;
    }
  } else if (y < ySq + nCh) {            // ---- chain: W_dst = csc*W_src + W_src.E ----
    const int t = y - ySq;
    f32x4 acc[2][2];
    gemm64sk(chWB + (size_t)t * WSZ, chE, LP, LP / 64, 0, 0, n0, tid, ldsA, ldsB, acc);
    if (tid < 256) {
      const float*  srcF = chWFsrc + (size_t)t * WSZ;
      float*        dstF = chWFdst + (size_t)t * WSZ;
      ushort*       dstB = chWBdst + (size_t)t * WSZ;
#pragma unroll
      for (int fm = 0; fm < 2; ++fm)
#pragma unroll
        for (int fn = 0; fn < 2; ++fn)
#pragma unroll
          for (int rr = 0; rr < 4; ++rr) {
            int mi = wm + fm * 16 + lg * 4 + rr;
            int ni = n0 + wn + fn * 16 + lr;
            float v = acc[fm][fn][rr] + csc * srcF[(size_t)mi * LP + ni];
            dstF[(size_t)mi * LP + ni] = v;
            dstB[(size_t)mi * LP + ni] = f2b(v);
          }
    }
  } else {                               // ---- kd ----
    int j = kdJ0 + (y - ySq - nCh);
    kd_body(kdWF, kdKDT, j, n0, tid, (float(*)[65])ldsA);
  }
}

// ========== kd j=32..63 (32 y) || conv z=0..2 (12 y) — conv reads KDT j<=31 (done in L6),
// kd here writes only j>=32 (read by conv z>=3 in the NEXT launch). Disjoint => safe. ==========
__global__ __launch_bounds__(512, 4) void k_kdcv(const float* __restrict__ WF,
                                                 ushort* __restrict__ KDT,
                                                 const ushort* __restrict__ U,
                                                 float* __restrict__ part) {
  __shared__ __align__(16) ushort ldsA[2 * LGRP];
  __shared__ __align__(16) ushort ldsB[2 * LGRP];
  const int tid = threadIdx.x;
  const int y = blockIdx.y;
  const int n0 = blockIdx.x * 64;
  if (y < 32) {
    kd_body(WF, KDT, 32 + y, n0, tid, (float(*)[65])ldsA);
  } else {
    const int c = y - 32;                // 0..11
    const int z = c >> 2, m0 = (c & 3) * 64;
    const int wv = (tid & 255) >> 6, lane = tid & 63;
    const int wm = (wv >> 1) * 32, wn = (wv & 1) * 32;
    const int lr = lane & 15, lg = lane >> 4;
    f32x4 acc[2][2];
    gemm64sk(U, KDT, KCV, (KCV / NZ) / 64, z * (KCV / NZ), m0, n0, tid, ldsA, ldsB, acc);
    if (tid < 256) {
      float* pp = part + (size_t)z * (256 * LP);
#pragma unroll
      for (int fm = 0; fm < 2; ++fm)
#pragma unroll
        for (int fn = 0; fn < 2; ++fn)
#pragma unroll
          for (int rr = 0; rr < 4; ++rr) {
            int m = m0 + wm + fm * 16 + lg * 4 + rr;
            int n = n0 + wn + fn * 16 + lr;
            pp[(size_t)m * LP + n] = acc[fm][fn][rr];
          }
    }
  }
}

// ================= conv GEMM z=3..5 (512 thr) =================
__global__ __launch_bounds__(512, 4) void k_conv(const ushort* __restrict__ U,
                                                 const ushort* __restrict__ KDT,
                                                 float* __restrict__ part) {
  __shared__ __align__(16) ushort ldsA[2 * LGRP];
  __shared__ __align__(16) ushort ldsB[2 * LGRP];
  const int tid = threadIdx.x;
  const int n0 = blockIdx.x * 64, m0 = blockIdx.y * 64;
  const int z = 3 + blockIdx.z;
  const int kOff = z * (KCV / NZ);
  const int wv = (tid & 255) >> 6, lane = tid & 63;
  const int wm = (wv >> 1) * 32, wn = (wv & 1) * 32;
  const int lr = lane & 15, lg = lane >> 4;
  f32x4 acc[2][2];
  gemm64sk(U, KDT, KCV, (KCV / NZ) / 64, kOff, m0, n0, tid, ldsA, ldsB, acc);
  if (tid < 256) {
    float* pp = part + (size_t)z * (256 * LP);
#pragma unroll
    for (int fm = 0; fm < 2; ++fm)
#pragma unroll
      for (int fn = 0; fn < 2; ++fn)
#pragma unroll
        for (int rr = 0; rr < 4; ++rr) {
          int m = m0 + wm + fm * 16 + lg * 4 + rr;
          int n = n0 + wn + fn * 16 + lr;
          pp[(size_t)m * LP + n] = acc[fm][fn][rr];
        }
  }
}

// ================= final: assemble theta row in LDS, decode =================
__global__ __launch_bounds__(256) void k_final(const float* __restrict__ part,
                                               const float* __restrict__ WF,
                                               const float* __restrict__ th0,
                                               const float* __restrict__ ts,
                                               float* __restrict__ out) {
  __shared__ float th[LP];
  const int bt = blockIdx.x, b = bt >> 6, t = bt & 63;
  for (int l = threadIdx.x; l < LP; l += 256) {
    float v = 0.f;
    if (l < L) {
      if (t == 0) v = th0[l];
      else {
        int rr = b * 63 + (t - 1);
        v = 0.f;
#pragma unroll
        for (int z = 0; z < NZ; ++z) v += part[(size_t)z * (256 * LP) + rr * LP + l];
        int tau = t - 1;
        v += WF[(size_t)tau * WSZ + DS * LP + l];       // A^tau @ theta0
        int tw = (tau + 62) % 63;
        v += WF[(size_t)tw * WSZ + (49 + b) * LP + l];  // A^{(tau-1)%63} @ sig1_b
      }
    }
    th[l] = v;
  }
  __syncthreads();
  int o = threadIdx.x;
  if (o < OUTD) {
    float tv = ts[bt];
    float acc = th[784 + o];
#pragma unroll
    for (int i = 0; i < 8; ++i) {
      float h = fmaxf(th[i] * tv + th[8 + i], 0.f);
      acc += th[16 + o * 8 + i] * h;
    }
    float rs;
    if (o < DS) rs = tanhf(acc);
    else        rs = fmaxf(acc, 0.f) + log1pf(expf(-fabsf(acc)));
    out[bt * OUTD + o] = rs;
  }
}

extern "C" void kernel_launch(void* const* d_in, const int* in_sizes, int n_in,
                              void* d_out, int out_size, void* d_ws, size_t ws_size,
                              hipStream_t stream) {
  const float* xs  = (const float*)d_in[0];
  const float* ts  = (const float*)d_in[1];
  const float* th0 = (const float*)d_in[2];
  const float* A   = (const float*)d_in[3];
  const float* B   = (const float*)d_in[4];
  float* out = (float*)d_out;
  float* ws  = (float*)d_ws;

  ushort* EP   = (ushort*)(ws + OFF_E);
  const size_t PL = (size_t)LP * LP;
  ushort* EN1  = EP + 0 * PL;
  ushort* ET1  = EP + 1 * PL;
  ushort* EN2  = EP + 2 * PL;
  ushort* ET2  = EP + 3 * PL;
  ushort* EN4  = EP + 4 * PL;
  ushort* ET4  = EP + 5 * PL;
  ushort* EN8  = EP + 6 * PL;
  ushort* ET8  = EP + 7 * PL;
  ushort* EN16 = EP + 8 * PL;
  ushort* ET16 = EP + 9 * PL;
  ushort* EN32 = EP + 10 * PL;
  float*  WF   = ws + OFF_WF;
  ushort* WB   = (ushort*)(ws + OFF_WB);
  ushort* KDT  = (ushort*)(ws + OFF_KDT);   // overlays E planes 0..3 (dead after L5)
  ushort* U    = (ushort*)(ws + OFF_U);
  float*  part = ws + OFF_PART;

  const float c1 = 0.99f;
  const float c2 = c1 * c1, c4 = c2 * c2, c8 = c4 * c4, c16 = c8 * c8, c32 = c16 * c16;

  k_prep<<<978, 256, 0, stream>>>(A, B, th0, xs, EN1, ET1, WF, WB, U);

  // L1..L5: sq E_S -> E_2S (14 rows) || chain W_{t+S} = c_S*W_t + W_t.E_S (S rows)
  k_ladder<<<dim3(14, 15), 512, 0, stream>>>(EN1, ET1, 2.f * c1, EN2, ET2, 14,
                                             1, WB, EN1, c1, WF, WF + 1 * WSZ, WB + (size_t)1 * WSZ,
                                             0, nullptr, nullptr);
  k_ladder<<<dim3(14, 16), 512, 0, stream>>>(EN2, ET2, 2.f * c2, EN4, ET4, 14,
                                             2, WB, EN2, c2, WF, WF + 2 * WSZ, WB + (size_t)2 * WSZ,
                                             0, nullptr, nullptr);
  k_ladder<<<dim3(14, 18), 512, 0, stream>>>(EN4, ET4, 2.f * c4, EN8, ET8, 14,
                                             4, WB, EN4, c4, WF, WF + 4 * WSZ, WB + (size_t)4 * WSZ,
                                             0, nullptr, nullptr);
  k_ladder<<<dim3(14, 22), 512, 0, stream>>>(EN8, ET8, 2.f * c8, EN16, ET16, 14,
                                             8, WB, EN8, c8, WF, WF + 8 * WSZ, WB + (size_t)8 * WSZ,
                                             0, nullptr, nullptr);
  k_ladder<<<dim3(14, 30), 512, 0, stream>>>(EN16, ET16, 2.f * c16, EN32, nullptr, 14,
                                             16, WB, EN16, c16, WF, WF + 16 * WSZ, WB + (size_t)16 * WSZ,
                                             0, nullptr, nullptr);
  // L6: chain W32..62 (31 rows) || kd j=0..31 (32 rows)
  k_ladder<<<dim3(14, 63), 512, 0, stream>>>(nullptr, nullptr, 0.f, nullptr, nullptr, 0,
                                             31, WB, EN32, c32, WF, WF + 32 * WSZ, WB + (size_t)32 * WSZ,
                                             0, WF, KDT);
  // kd j=32..63 || conv z=0..2
  k_kdcv<<<dim3(14, 44), 512, 0, stream>>>(WF, KDT, U, part);
  // conv z=3..5
  k_conv<<<dim3(14, 4, 3), 512, 0, stream>>>(U, KDT, part);
  k_final<<<256, 256, 0, stream>>>(part, WF, th0, ts, out);
}